// Round 6
// baseline (350.990 us; speedup 1.0000x reference)
//
#include <hip/hip_runtime.h>

typedef unsigned short u16;
typedef unsigned int u32;
typedef __attribute__((ext_vector_type(8))) short short8;
typedef __attribute__((ext_vector_type(4))) float floatx4;
typedef __attribute__((ext_vector_type(4))) u32 u32x4;

#define MDIM 4096
#define NDIM 4096
#define KDIM 4096
#define BM 256
#define BN 256
#define BK 64
#define LBUF 32768   // u16 per LDS double-buffer slot (64 KiB): A 2x8192 + B 2x8192
#define AOFF 0
#define BOFF 16384

// ---------------- fused fp32 GEMM, C = A * B^T + bias ----------------
// (Round-6 resubmission of the round-5 kernel: round 5 died to a broker/
// container infra failure with no counters; schedule ledger re-audited,
// no deadlock/OOB path found, code unchanged.)
//
// Single kernel: fp32->bf16 conversion fused into the staging path --
// deletes the separate cvt dispatch AND its 128 MB bf16 workspace
// write+read round-trip (the constant ~154 us of non-GEMM time, rounds 0-4).
//
// 256x256 tile, BK=64, 8 waves (2M x 4N), 128 KiB LDS, 4 phases/tile.
// Per phase, each thread:
//   - lookahead ds_reads of next phase's MFMA fragments (round-4 skeleton)
//   - cvt+write: 8x v_cvt_pk_bf16_f32 (RNE, == previous bit-trick RNE for
//     finite input) on regs loaded LAST phase, then 2x ds_write_b128 into
//     the same swizzled layout as before
//   - issue next phase's 4x global_load_dwordx4 (fp32, 64 B contiguous)
//   - 16 MFMA on fragments read last phase (order unchanged -> numerics
//     bit-identical to the round-4 kernel)
//   - lgkmcnt(0) (local, retires under the MFMA cluster) + s_barrier:
//     closes every cross-wave LDS WAR/RAW window at each phase boundary.
//     No manual vmcnt: staging loads are C-level, the compiler emits exact
//     counted vmcnt before the cvt uses.
//
// LDS swizzle (verified, bank conflicts = 0): half-region =
// [128 ldsrows][8 slots][8 u16]; chunk ci -> ldsrow=ci>>3, slot=ci&7,
// global chunk c=(ci&7)^(ldsrow&7), row r=2*ldsrow+(c>>2), kk=(c&3)*8.
// Thread t stages chunks {t, 512+t}: LDS writes at t*16B and 8192B+t*16B
// (16 B/lane stride -> conflict-free); global source = 2x 32 B segments.
//
// Staging region map per tile T (buffer b=T&1):
//  p1: CW (b^1,A,h1) [T+1] | LD B delta  96 [T+1 h1]
//  p2: CW (b^1,B,h1)       | LD A delta 128 [T+2 h0]
//  p3: CW (b,  A,h0) [T+2] | LD B delta 128
//  p4: CW (b,  B,h0)       | LD A delta 160 [T+2 h1]
// (deltas in floats from ptr = base + T*64; ptr bumps +64 at tile end)
// WAR safety: lgkmcnt(0) per phase retires all LDS ops before each barrier;
// every CW targets a region whose last fragment read was >=1 barrier
// earlier (region ledger re-verified, tiles 0..63 incl. tail).

typedef const __attribute__((address_space(1))) void* gas_ptr;
typedef __attribute__((address_space(3))) void* lds_ptr;

__global__ __launch_bounds__(512, 2) void gemm_fused_bias(const float* __restrict__ A,
                                                          const float* __restrict__ B,
                                                          const float* __restrict__ bias,
                                                          float* __restrict__ C) {
    __shared__ u16 lds[2 * LBUF];   // 128 KiB

    const int t = threadIdx.x;
    const int bm0 = blockIdx.y * BM;
    const int bn0 = blockIdx.x * BN;

    const int wave = t >> 6;
    const int lane = t & 63;
    const int wmi = wave >> 2;          // 0..1  (M wave index, 128 rows each)
    const int wni = wave & 3;           // 0..3  (N wave index, 64 cols each)
    const int lr = lane & 15;           // fragment row within 16
    const int q  = lane >> 4;           // k-quad 0..3

    // staging source pointers (fp32), chunks ci = t and ci = 512 + t
    const float* gA0; const float* gA1; const float* gB0; const float* gB1;
    {
        int ci = t;
        int ldsrow = ci >> 3;
        int c = (ci & 7) ^ (ldsrow & 7);
        int r = 2 * ldsrow + (c >> 2);
        int kk = (c & 3) * 8;
        gA0 = A + (size_t)(bm0 + r) * KDIM + kk;
        gB0 = B + (size_t)(bn0 + r) * KDIM + kk;
        ci = 512 + t;
        ldsrow = ci >> 3;
        c = (ci & 7) ^ (ldsrow & 7);
        r = 2 * ldsrow + (c >> 2);
        kk = (c & 3) * 8;
        gA1 = A + (size_t)(bm0 + r) * KDIM + kk;
        gB1 = B + (size_t)(bn0 + r) * KDIM + kk;
    }

    // fragment-read lane constants (slot is frag-index independent)
    const int aslot = (((lr & 1) << 2) + q) ^ ((lr >> 1) & 7);
    const int aLane = (wmi * 64 + (lr >> 1)) * 64 + aslot * 8;   // + i*512
    const int bLane = (wni * 32 + (lr >> 1)) * 64 + aslot * 8;   // + j*512

    floatx4 acc[8][4] = {};
    short8 afA[4], afB[4], bfA[4], bfB[4];
    float4 s0, s1, s2, s3;       // staging regs (one half-region / thread-slice)
    float4 r0, r1, r2, r3;       // second buffer (prologue pipeline only)

#define CVTPK(W, LO, HI) asm("v_cvt_pk_bf16_f32 %0, %1, %2" : "=v"(W) : "v"(LO), "v"(HI))

// convert 16 fp32 (x0..x3) -> 16 bf16, write 2x b128 to swizzled region
#define CW(X0, X1, X2, X3, CUR, MATOFF, H) do { \
    u32 w0, w1, w2, w3, w4, w5, w6, w7; \
    CVTPK(w0, X0.x, X0.y); CVTPK(w1, X0.z, X0.w); \
    CVTPK(w2, X1.x, X1.y); CVTPK(w3, X1.z, X1.w); \
    CVTPK(w4, X2.x, X2.y); CVTPK(w5, X2.z, X2.w); \
    CVTPK(w6, X3.x, X3.y); CVTPK(w7, X3.z, X3.w); \
    u32x4 v0; v0[0] = w0; v0[1] = w1; v0[2] = w2; v0[3] = w3; \
    u32x4 v1; v1[0] = w4; v1[1] = w5; v1[2] = w6; v1[3] = w7; \
    *(u32x4*)&lds[(CUR) * LBUF + (MATOFF) + (H) * 8192 + t * 8] = v0; \
    *(u32x4*)&lds[(CUR) * LBUF + (MATOFF) + (H) * 8192 + 4096 + t * 8] = v1; \
} while (0)

// issue 4x global_load_dwordx4 (64 B fp32 / thread) for next phase's CW
#define LD4(X0, X1, X2, X3, P0, P1, DF) do { \
    X0 = *(const float4*)((P0) + (DF)); \
    X1 = *(const float4*)((P0) + (DF) + 4); \
    X2 = *(const float4*)((P1) + (DF)); \
    X3 = *(const float4*)((P1) + (DF) + 4); \
} while (0)

#define RD_AF(DST, CUR, H, I0) do { \
    const u16* _p = lds + (CUR) * LBUF + (H) * 8192 + aLane; \
    DST[0] = *(const short8*)(_p + ((I0) + 0) * 512); \
    DST[1] = *(const short8*)(_p + ((I0) + 1) * 512); \
    DST[2] = *(const short8*)(_p + ((I0) + 2) * 512); \
    DST[3] = *(const short8*)(_p + ((I0) + 3) * 512); \
} while (0)

#define RD_BF(DST, CUR, H) do { \
    const u16* _q = lds + (CUR) * LBUF + BOFF + (H) * 8192 + bLane; \
    DST[0] = *(const short8*)(_q + 0 * 512); \
    DST[1] = *(const short8*)(_q + 1 * 512); \
    DST[2] = *(const short8*)(_q + 2 * 512); \
    DST[3] = *(const short8*)(_q + 3 * 512); \
} while (0)

#define MFMA16(AF, BF, IOFF) do { \
    _Pragma("unroll") \
    for (int i2 = 0; i2 < 4; ++i2) { \
        _Pragma("unroll") \
        for (int j = 0; j < 4; ++j) \
            acc[(IOFF) + i2][j] = __builtin_amdgcn_mfma_f32_16x16x32_bf16( \
                AF[i2], BF[j], acc[(IOFF) + i2][j], 0, 0, 0); \
    } \
} while (0)

#define SCB() __builtin_amdgcn_sched_barrier(0)
#define PRIO1 __builtin_amdgcn_s_setprio(1)
#define PRIO0 __builtin_amdgcn_s_setprio(0)
// lgkm drain (local, completes under the MFMA cluster) + barrier
#define LGKM0_BAR() do { \
    SCB(); asm volatile("s_waitcnt lgkmcnt(0)"); SCB(); \
    __builtin_amdgcn_s_barrier(); SCB(); \
} while (0)

#define KTILE(CUR, DO12, DO34, NX12, P4RD) do { \
    /* p1 */ \
    RD_AF(afB, CUR, 0, 4); \
    if (DO12) CW(s0, s1, s2, s3, (CUR) ^ 1, AOFF, 1); \
    if (DO12) LD4(s0, s1, s2, s3, gB0, gB1, 96); \
    SCB(); PRIO1; MFMA16(afA, bfA, 0); PRIO0; LGKM0_BAR(); \
    /* p2 */ \
    RD_AF(afA, CUR, 1, 0); RD_BF(bfB, CUR, 1); \
    if (DO12) CW(s0, s1, s2, s3, (CUR) ^ 1, BOFF, 1); \
    if (DO34) LD4(s0, s1, s2, s3, gA0, gA1, 128); \
    SCB(); PRIO1; MFMA16(afB, bfA, 4); PRIO0; LGKM0_BAR(); \
    /* p3 */ \
    RD_AF(afB, CUR, 1, 4); \
    if (DO34) CW(s0, s1, s2, s3, CUR, AOFF, 0); \
    if (DO34) LD4(s0, s1, s2, s3, gB0, gB1, 128); \
    SCB(); PRIO1; MFMA16(afA, bfB, 0); PRIO0; LGKM0_BAR(); \
    /* p4 */ \
    if (P4RD) { RD_AF(afA, (CUR) ^ 1, 0, 0); RD_BF(bfA, (CUR) ^ 1, 0); } \
    if (DO34) CW(s0, s1, s2, s3, CUR, BOFF, 0); \
    if (NX12) LD4(s0, s1, s2, s3, gA0, gA1, 160); \
    SCB(); PRIO1; MFMA16(afB, bfB, 4); PRIO0; LGKM0_BAR(); \
    gA0 += BK; gA1 += BK; gB0 += BK; gB1 += BK; \
} while (0)

    // ---- prologue: stage T0 {A,B}x{h0,h1} + T1 {A,B}h0, 2-deep pipelined;
    // then pre-load S for tile0.p1's CW (= T1 A h1, delta 96)
    LD4(s0, s1, s2, s3, gA0, gA1, 0);                       // T0 A h0
    LD4(r0, r1, r2, r3, gB0, gB1, 0);                       // T0 B h0
    CW(s0, s1, s2, s3, 0, AOFF, 0);
    LD4(s0, s1, s2, s3, gA0, gA1, 32);                      // T0 A h1
    CW(r0, r1, r2, r3, 0, BOFF, 0);
    LD4(r0, r1, r2, r3, gB0, gB1, 32);                      // T0 B h1
    CW(s0, s1, s2, s3, 0, AOFF, 1);
    LD4(s0, s1, s2, s3, gA0, gA1, 64);                      // T1 A h0
    CW(r0, r1, r2, r3, 0, BOFF, 1);
    LD4(r0, r1, r2, r3, gB0, gB1, 64);                      // T1 B h0
    CW(s0, s1, s2, s3, 1, AOFF, 0);
    CW(r0, r1, r2, r3, 1, BOFF, 0);
    LD4(s0, s1, s2, s3, gA0, gA1, 96);                      // T1 A h1 (for t0.p1 CW)
    LGKM0_BAR();
    RD_AF(afA, 0, 0, 0);
    RD_BF(bfA, 0, 0);

    // ---- main loop: tiles 0..61 ----
    for (int it = 0; it < 31; ++it) {
        KTILE(0, 1, 1, 1, 1);
        KTILE(1, 1, 1, 1, 1);
    }
    // ---- tail: tile 62 stages T63.h1 only; tile 63 stages nothing ----
    KTILE(0, 1, 0, 0, 1);
    KTILE(1, 0, 0, 0, 0);

    // ---- epilogue: C/D layout col=lane&15, row=(lane>>4)*4+qq [m89-verified]
#pragma unroll
    for (int j = 0; j < 4; ++j) {
        const int col = bn0 + wni * 64 + j * 16 + lr;
        const float bv = bias[col];
#pragma unroll
        for (int i = 0; i < 8; ++i) {
            const int row0 = bm0 + wmi * 128 + i * 16 + q * 4;
#pragma unroll
            for (int qq = 0; qq < 4; ++qq)
                C[(size_t)(row0 + qq) * NDIM + col] = acc[i][j][qq] + bv;
        }
    }

#undef CVTPK
#undef CW
#undef LD4
#undef RD_AF
#undef RD_BF
#undef MFMA16
#undef SCB
#undef PRIO1
#undef PRIO0
#undef LGKM0_BAR
#undef KTILE
}

extern "C" void kernel_launch(void* const* d_in, const int* in_sizes, int n_in,
                              void* d_out, int out_size, void* d_ws, size_t ws_size,
                              hipStream_t stream) {
    const float* x = (const float*)d_in[0];      // (4096, 4096) fp32
    const float* w = (const float*)d_in[1];      // (4096, 4096) fp32, OUT x IN
    const float* bias = (const float*)d_in[2];   // (4096,) fp32
    float* out = (float*)d_out;                  // (4096, 4096) fp32

    dim3 grid(NDIM / BN, MDIM / BM);             // 16 x 16
    gemm_fused_bias<<<grid, dim3(512), 0, stream>>>(x, w, bias, out);
}

// Round 7
// 302.811 us; speedup vs baseline: 1.1591x; 1.1591x over previous
//
#include <hip/hip_runtime.h>

typedef unsigned short u16;
typedef unsigned int u32;
typedef __attribute__((ext_vector_type(8))) short short8;
typedef __attribute__((ext_vector_type(4))) float floatx4;
typedef __attribute__((ext_vector_type(4))) u32 u32x4;

#define MDIM 4096
#define NDIM 4096
#define KDIM 4096
#define BM 256
#define BN 256
#define BK 64
#define LBUF 32768   // u16 per LDS double-buffer slot (64 KiB): A 2x8192 + B 2x8192
#define AOFF 0
#define BOFF 16384

// ---------------- fused fp32 GEMM, C = A * B^T + bias ----------------
// Round-7: fusion retained, two root causes of round-6's 246us fixed:
//  (1) VGPR cap: 1 block/CU (128K LDS) => 2 waves/SIMD => 256 unified
//      VGPR/wave. acc=128 AGPR leaves 128 arch. Round-4 used exactly 128;
//      round-6's +staging regs pushed past the cap (spill/serialization).
//      Fix: DROP the fragment double-buffer (-32 regs) -- MFMA waits
//      same-phase lgkmcnt(0) (round-1 structure, measured ~4% MfmaUtil
//      below lookahead). Arch estimate ~95-110 <= 128.
//  (2) staging loads had 1-phase flight + same-reg WAR => per-phase vmcnt
//      stall. Fix: two buffers X/Y, 2-PHASE consume distance:
//      X: LD@p1 -> CW@p3, LD@p3 -> CW@(T+1).p1;  Y: LD@p2 -> CW@p4,
//      LD@p4 -> CW@(T+1).p2. 8 loads outstanding, compiler inserts counted
//      vmcnt(4) before each CW -- never a drain-to-0, >=2 phases of flight.
//
// LDS swizzle (verified, bank conflicts = 0): half-region =
// [128 ldsrows][8 slots][8 u16]; chunk ci -> ldsrow=ci>>3, slot=ci&7,
// global chunk c=(ci&7)^(ldsrow&7), row r=2*ldsrow+(c>>2), kk=(c&3)*8.
// Thread t stages chunks {t, 512+t}: LDS writes at t*16B and 8192B+t*16B
// (conflict-free); global source = 2x 32B segments (2 float4 at +0/+16).
//
// Per tile T (buffer b=T&1), 4 phases, phase = { frag ds_reads; CW(cvt 8x
// v_cvt_pk_bf16_f32 + 2x ds_write_b128); LD4 next; lgkmcnt(0); MFMA x16;
// s_barrier }:
//  p1: rd af=h0.m0-3, bf=h0 | CW X->(b^1,A,h1)[T+1] | LD X=A@128 | MFMA acc0
//  p2: rd af=h0.m4-7        | CW Y->(b^1,B,h1)      | LD Y=B@128 | MFMA acc4
//  p3: rd af=h1.m0-3, bf=h1 | CW X->(b,A,h0)[T+2]   | LD X=A@160 | MFMA acc0
//  p4: rd af=h1.m4-7        | CW Y->(b,B,h0)        | LD Y=B@160 | MFMA acc4
// (deltas in floats from tile base; pointers bump +64/tile)
// Region ledger: CW targets were last frag-read >=2 barriers earlier; each
// wave's lgkmcnt(0) retires its ds ops before its barrier => no cross-wave
// WAR/RAW. MFMA k-order identical to rounds 0-6 => bit-identical output.
// Tail: tile62 only CW12 (consumes tile61's loads; its own LDs would be
// k=4096 OOB -> disabled); tile63 compute-only.

__global__ __launch_bounds__(512, 2) void gemm_fused_bias(const float* __restrict__ A,
                                                          const float* __restrict__ B,
                                                          const float* __restrict__ bias,
                                                          float* __restrict__ C) {
    __shared__ u16 lds[2 * LBUF];   // 128 KiB

    const int t = threadIdx.x;
    const int bm0 = blockIdx.y * BM;
    const int bn0 = blockIdx.x * BN;

    const int wave = t >> 6;
    const int lane = t & 63;
    const int wmi = wave >> 2;          // 0..1  (M wave index, 128 rows each)
    const int wni = wave & 3;           // 0..3  (N wave index, 64 cols each)
    const int lr = lane & 15;           // fragment row within 16
    const int q  = lane >> 4;           // k-quad 0..3

    // staging source pointers (fp32), chunks ci = t and ci = 512 + t
    const float* gA0; const float* gA1; const float* gB0; const float* gB1;
    {
        int ci = t;
        int ldsrow = ci >> 3;
        int c = (ci & 7) ^ (ldsrow & 7);
        int r = 2 * ldsrow + (c >> 2);
        int kk = (c & 3) * 8;
        gA0 = A + (size_t)(bm0 + r) * KDIM + kk;
        gB0 = B + (size_t)(bn0 + r) * KDIM + kk;
        ci = 512 + t;
        ldsrow = ci >> 3;
        c = (ci & 7) ^ (ldsrow & 7);
        r = 2 * ldsrow + (c >> 2);
        kk = (c & 3) * 8;
        gA1 = A + (size_t)(bm0 + r) * KDIM + kk;
        gB1 = B + (size_t)(bn0 + r) * KDIM + kk;
    }

    // fragment-read lane constants (slot is frag-index independent)
    const int aslot = (((lr & 1) << 2) + q) ^ ((lr >> 1) & 7);
    const int aLane = (wmi * 64 + (lr >> 1)) * 64 + aslot * 8;   // + i*512
    const int bLane = (wni * 32 + (lr >> 1)) * 64 + aslot * 8;   // + j*512

    floatx4 acc[8][4] = {};
    short8 af[4], bf[4];                     // single-buffer fragments
    float4 x0, x1, x2, x3;                   // staging buffer X (A-path)
    float4 y0, y1, y2, y3;                   // staging buffer Y (B-path)

#define CVTPK(W, LO, HI) asm("v_cvt_pk_bf16_f32 %0, %1, %2" : "=v"(W) : "v"(LO), "v"(HI))

// convert 16 fp32 -> 16 bf16, write 2x b128 to swizzled region
#define CW(X0, X1, X2, X3, CUR, MATOFF, H) do { \
    u32 w0, w1, w2, w3, w4, w5, w6, w7; \
    CVTPK(w0, X0.x, X0.y); CVTPK(w1, X0.z, X0.w); \
    CVTPK(w2, X1.x, X1.y); CVTPK(w3, X1.z, X1.w); \
    CVTPK(w4, X2.x, X2.y); CVTPK(w5, X2.z, X2.w); \
    CVTPK(w6, X3.x, X3.y); CVTPK(w7, X3.z, X3.w); \
    u32x4 v0; v0[0] = w0; v0[1] = w1; v0[2] = w2; v0[3] = w3; \
    u32x4 v1; v1[0] = w4; v1[1] = w5; v1[2] = w6; v1[3] = w7; \
    *(u32x4*)&lds[(CUR) * LBUF + (MATOFF) + (H) * 8192 + t * 8] = v0; \
    *(u32x4*)&lds[(CUR) * LBUF + (MATOFF) + (H) * 8192 + 4096 + t * 8] = v1; \
} while (0)

// issue 4x global_load_dwordx4 (64 B fp32 / thread)
#define LD4(X0, X1, X2, X3, P0, P1, DF) do { \
    X0 = *(const float4*)((P0) + (DF)); \
    X1 = *(const float4*)((P0) + (DF) + 4); \
    X2 = *(const float4*)((P1) + (DF)); \
    X3 = *(const float4*)((P1) + (DF) + 4); \
} while (0)

#define RD_AF(CUR, H, I0) do { \
    const u16* _p = lds + (CUR) * LBUF + (H) * 8192 + aLane; \
    af[0] = *(const short8*)(_p + ((I0) + 0) * 512); \
    af[1] = *(const short8*)(_p + ((I0) + 1) * 512); \
    af[2] = *(const short8*)(_p + ((I0) + 2) * 512); \
    af[3] = *(const short8*)(_p + ((I0) + 3) * 512); \
} while (0)

#define RD_BF(CUR, H) do { \
    const u16* _q = lds + (CUR) * LBUF + BOFF + (H) * 8192 + bLane; \
    bf[0] = *(const short8*)(_q + 0 * 512); \
    bf[1] = *(const short8*)(_q + 1 * 512); \
    bf[2] = *(const short8*)(_q + 2 * 512); \
    bf[3] = *(const short8*)(_q + 3 * 512); \
} while (0)

#define MFMA16(IOFF) do { \
    _Pragma("unroll") \
    for (int i2 = 0; i2 < 4; ++i2) { \
        _Pragma("unroll") \
        for (int j = 0; j < 4; ++j) \
            acc[(IOFF) + i2][j] = __builtin_amdgcn_mfma_f32_16x16x32_bf16( \
                af[i2], bf[j], acc[(IOFF) + i2][j], 0, 0, 0); \
    } \
} while (0)

#define SCB() __builtin_amdgcn_sched_barrier(0)
#define PRIO1 __builtin_amdgcn_s_setprio(1)
#define PRIO0 __builtin_amdgcn_s_setprio(0)
#define LGKM0() do { SCB(); asm volatile("s_waitcnt lgkmcnt(0)"); SCB(); } while (0)
#define BAR() do { SCB(); __builtin_amdgcn_s_barrier(); SCB(); } while (0)

#define KTILE(CUR, CW12, CW34, LD12, LD34) do { \
    /* p1 */ \
    RD_AF(CUR, 0, 0); RD_BF(CUR, 0); \
    if (CW12) CW(x0, x1, x2, x3, (CUR) ^ 1, AOFF, 1); \
    if (LD12) LD4(x0, x1, x2, x3, gA0, gA1, 128); \
    LGKM0(); PRIO1; MFMA16(0); PRIO0; BAR(); \
    /* p2 */ \
    RD_AF(CUR, 0, 4); \
    if (CW12) CW(y0, y1, y2, y3, (CUR) ^ 1, BOFF, 1); \
    if (LD12) LD4(y0, y1, y2, y3, gB0, gB1, 128); \
    LGKM0(); PRIO1; MFMA16(4); PRIO0; BAR(); \
    /* p3 */ \
    RD_AF(CUR, 1, 0); RD_BF(CUR, 1); \
    if (CW34) CW(x0, x1, x2, x3, CUR, AOFF, 0); \
    if (LD34) LD4(x0, x1, x2, x3, gA0, gA1, 160); \
    LGKM0(); PRIO1; MFMA16(0); PRIO0; BAR(); \
    /* p4 */ \
    RD_AF(CUR, 1, 4); \
    if (CW34) CW(y0, y1, y2, y3, CUR, BOFF, 0); \
    if (LD34) LD4(y0, y1, y2, y3, gB0, gB1, 160); \
    LGKM0(); PRIO1; MFMA16(4); PRIO0; BAR(); \
    gA0 += BK; gA1 += BK; gB0 += BK; gB1 += BK; \
} while (0)

    // ---- prologue: stage T0 {A,B}x{h0,h1} + T1 {A,B}h0 via X/Y ping-pong,
    // then leave X = A@96 (T1.A.h1), Y = B@96 in flight for tile0's CW12.
    LD4(x0, x1, x2, x3, gA0, gA1, 0);                       // T0 A h0
    LD4(y0, y1, y2, y3, gB0, gB1, 0);                       // T0 B h0
    CW(x0, x1, x2, x3, 0, AOFF, 0);
    LD4(x0, x1, x2, x3, gA0, gA1, 32);                      // T0 A h1
    CW(y0, y1, y2, y3, 0, BOFF, 0);
    LD4(y0, y1, y2, y3, gB0, gB1, 32);                      // T0 B h1
    CW(x0, x1, x2, x3, 0, AOFF, 1);
    LD4(x0, x1, x2, x3, gA0, gA1, 64);                      // T1 A h0
    CW(y0, y1, y2, y3, 0, BOFF, 1);
    LD4(y0, y1, y2, y3, gB0, gB1, 64);                      // T1 B h0
    CW(x0, x1, x2, x3, 1, AOFF, 0);
    CW(y0, y1, y2, y3, 1, BOFF, 0);
    LD4(x0, x1, x2, x3, gA0, gA1, 96);                      // T1 A h1 (tile0.p1 CW)
    LD4(y0, y1, y2, y3, gB0, gB1, 96);                      // T1 B h1 (tile0.p2 CW)
    LGKM0();
    BAR();

    // ---- main loop: tiles 0..61, full schedule ----
    for (int it = 0; it < 31; ++it) {
        KTILE(0, 1, 1, 1, 1);
        KTILE(1, 1, 1, 1, 1);
    }
    // ---- tail: tile62 writes T63.h1 (consumes tile61's p3/p4 loads),
    //            no new loads (k=4096 would be OOB); tile63 compute-only.
    KTILE(0, 1, 0, 0, 0);
    KTILE(1, 0, 0, 0, 0);

    // ---- epilogue: C/D layout col=lane&15, row=(lane>>4)*4+qq [m89-verified]
#pragma unroll
    for (int j = 0; j < 4; ++j) {
        const int col = bn0 + wni * 64 + j * 16 + lr;
        const float bv = bias[col];
#pragma unroll
        for (int i = 0; i < 8; ++i) {
            const int row0 = bm0 + wmi * 128 + i * 16 + q * 4;
#pragma unroll
            for (int qq = 0; qq < 4; ++qq)
                C[(size_t)(row0 + qq) * NDIM + col] = acc[i][j][qq] + bv;
        }
    }

#undef CVTPK
#undef CW
#undef LD4
#undef RD_AF
#undef RD_BF
#undef MFMA16
#undef SCB
#undef PRIO1
#undef PRIO0
#undef LGKM0
#undef BAR
#undef KTILE
}

extern "C" void kernel_launch(void* const* d_in, const int* in_sizes, int n_in,
                              void* d_out, int out_size, void* d_ws, size_t ws_size,
                              hipStream_t stream) {
    const float* x = (const float*)d_in[0];      // (4096, 4096) fp32
    const float* w = (const float*)d_in[1];      // (4096, 4096) fp32, OUT x IN
    const float* bias = (const float*)d_in[2];   // (4096,) fp32
    float* out = (float*)d_out;                  // (4096, 4096) fp32

    dim3 grid(NDIM / BN, MDIM / BM);             // 16 x 16
    gemm_fused_bias<<<grid, dim3(512), 0, stream>>>(x, w, bias, out);
}